// Round 7
// baseline (317.455 us; speedup 1.0000x reference)
//
#include <hip/hip_runtime.h>
#include <hip/hip_bf16.h>
#include <cfloat>

// dims
#define N_B 32
#define QN 64
#define FN 16
#define LP 196
#define HN 12
#define DH 64
#define EE 768
#define KLEN 3136
#define FPB 2          // frames per block (attn): 12*8*32 = 3072 blocks = 3.0 CU-rounds
#define KROWS 208      // padded patches per frame for QK (13*16)
#define VST 256        // Vt_s row stride in bf16 (512B, pow2 for XOR swizzle)

typedef short s16x4 __attribute__((ext_vector_type(4)));
typedef __bf16 bf16x8 __attribute__((ext_vector_type(8)));
typedef float f32x4 __attribute__((ext_vector_type(4)));
typedef unsigned u32x4 __attribute__((ext_vector_type(4)));

__device__ __forceinline__ bf16x8 cvt8(f32x4 a, f32x4 b) {
    bf16x8 r;
    r[0] = (__bf16)a[0]; r[1] = (__bf16)a[1]; r[2] = (__bf16)a[2]; r[3] = (__bf16)a[3];
    r[4] = (__bf16)b[0]; r[5] = (__bf16)b[1]; r[6] = (__bf16)b[2]; r[7] = (__bf16)b[3];
    return r;
}
__device__ __forceinline__ unsigned short bfb(float x) {
    return __builtin_bit_cast(unsigned short, (__bf16)x);
}
__device__ __forceinline__ unsigned pkbf(float lo, float hi) {
    return (unsigned)bfb(lo) | ((unsigned)bfb(hi) << 16);
}

// ---------------------------------------------------------------------------
// bf16 MFMA GEMM: C[m][n] = sum_k A[m][k] * W[n][k]  (fp32 in, fp32 out)
// ---------------------------------------------------------------------------
__global__ __launch_bounds__(256) void gemm_mfma(const float* __restrict__ A,
                                                 const float* __restrict__ W,
                                                 float* __restrict__ C) {
    __shared__ unsigned short As[64 * 72];
    __shared__ unsigned short Ws[48 * 72];
    const int t = threadIdx.x;
    const int w = t >> 6, lane = t & 63, lr = lane & 15, lg = lane >> 4;
    const int m0 = blockIdx.x * 64;
    const int n0 = blockIdx.y * 48;

    f32x4 acc[3];
#pragma unroll
    for (int ct = 0; ct < 3; ++ct) acc[ct] = (f32x4){0.f, 0.f, 0.f, 0.f};

    for (int k0 = 0; k0 < EE; k0 += 32) {
        {
            int row = t >> 2, cb = t & 3;
            const float* src = A + (size_t)(m0 + row) * EE + k0 + cb * 8;
            f32x4 a = *(const f32x4*)src, b = *(const f32x4*)(src + 4);
            *(bf16x8*)&As[row * 72 + cb * 8] = cvt8(a, b);
        }
        if (t < 192) {
            int row = t >> 2, cb = t & 3;
            const float* src = W + (size_t)(n0 + row) * EE + k0 + cb * 8;
            f32x4 a = *(const f32x4*)src, b = *(const f32x4*)(src + 4);
            *(bf16x8*)&Ws[row * 72 + cb * 8] = cvt8(a, b);
        }
        __syncthreads();
        bf16x8 a = *(const bf16x8*)&As[(w * 16 + lr) * 72 + lg * 8];
#pragma unroll
        for (int ct = 0; ct < 3; ++ct) {
            bf16x8 b = *(const bf16x8*)&Ws[(ct * 16 + lr) * 72 + lg * 8];
            acc[ct] = __builtin_amdgcn_mfma_f32_16x16x32_bf16(a, b, acc[ct], 0, 0, 0);
        }
        __syncthreads();
    }
#pragma unroll
    for (int ct = 0; ct < 3; ++ct)
#pragma unroll
        for (int r = 0; r < 4; ++r)
            C[(size_t)(m0 + w * 16 + lg * 4 + r) * EE + n0 + ct * 16 + lr] = acc[ct][r];
}

__global__ __launch_bounds__(256) void zero_f32(float* __restrict__ p, int n4) {
    int i = blockIdx.x * 256 + threadIdx.x;
    if (i < n4) ((float4*)p)[i] = make_float4(0.f, 0.f, 0.f, 0.f);
}

// ---------------------------------------------------------------------------
// MFMA attention, 33.7 KB LDS -> 4 blocks/CU. Block = (h, frame-group, n);
// 4 waves; wave w owns queries [w*16, w*16+16). Per frame: K staged to
// swizzled [208][64] LDS; QK^T scores in regs (col=q); register softmax;
// P redistributed to PV A-fragments via in-register shfl_xor (no Pt LDS);
// V staged transposed (swizzled, stride 256); PV; atomicAdd into mix.
// ---------------------------------------------------------------------------
__global__ __launch_bounds__(256, 4) void attn_mfma(const float* __restrict__ qs_g,
                                                    const float* __restrict__ k_g,
                                                    const float* __restrict__ v_g,
                                                    const int* __restrict__ m_g,
                                                    float* __restrict__ mix_g) {
    const int h = blockIdx.x, fg = blockIdx.y, n = blockIdx.z;

    __shared__ __attribute__((aligned(16))) unsigned short KV_s[64 * VST]; // K view: [208][64] swz; Vt view: [64][256] swz
    __shared__ __attribute__((aligned(16))) float bias_s[224];

    const int t = threadIdx.x;
    const int w = t >> 6, lane = t & 63, lr = lane & 15, lg = lane >> 4;

    // Q fragments straight to registers (scaled by d^-0.5)
    bf16x8 qb0, qb1;
    {
        const float* qp = qs_g + ((size_t)n * QN + w * 16 + lr) * EE + h * DH + lg * 8;
        f32x4 a = *(const f32x4*)qp, b = *(const f32x4*)(qp + 4);
        f32x4 c = *(const f32x4*)(qp + 32), d = *(const f32x4*)(qp + 36);
#pragma unroll
        for (int i = 0; i < 4; ++i) { a[i] *= 0.125f; b[i] *= 0.125f; c[i] *= 0.125f; d[i] *= 0.125f; }
        qb0 = cvt8(a, b);
        qb1 = cvt8(c, d);
    }

    float mix[4][4];
#pragma unroll
    for (int dt = 0; dt < 4; ++dt)
#pragma unroll
        for (int r = 0; r < 4; ++r) mix[dt][r] = 0.f;

    for (int ff = 0; ff < FPB; ++ff) {
        const size_t kbase = (size_t)n * KLEN + (size_t)(fg * FPB + ff) * LP;

        __syncthreads();  // prev-frame PV / softmax readers done before overwrite

        // ---- stage K [208][64] bf16, XOR-swizzled 16B blocks (g = p&7) ----
#pragma unroll
        for (int u = 0; u < 7; ++u) {
            int unit = t + 256 * u;
            if (unit < KROWS * 8) {
                int p = unit >> 3, blk = unit & 7;
                f32x4 a = {0.f, 0.f, 0.f, 0.f}, b = {0.f, 0.f, 0.f, 0.f};
                if (p < LP) {
                    const float* src = k_g + ((kbase + p) * HN + h) * DH + blk * 8;
                    a = *(const f32x4*)src;
                    b = *(const f32x4*)(src + 4);
                }
                *(bf16x8*)&KV_s[p * 64 + ((blk ^ (p & 7)) << 3)] = cvt8(a, b);
            }
        }
        if (t < 224) {
            float bv = -1e30f;
            if (t < LP && m_g[kbase + t] != 0) bv = 0.f;
            bias_s[t] = bv;
        }
        __syncthreads();

        // ---- QK^T: lane holds scores for q = w*16+lr, p = tl*16 + lg*4 + r ----
        f32x4 sc[13];
#pragma unroll
        for (int tl = 0; tl < 13; ++tl) {
            int row = tl * 16 + lr;
            bf16x8 a0 = *(const bf16x8*)&KV_s[row * 64 + ((lg ^ (lr & 7)) << 3)];
            bf16x8 a1 = *(const bf16x8*)&KV_s[row * 64 + (((4 + lg) ^ (lr & 7)) << 3)];
            f32x4 z = {0.f, 0.f, 0.f, 0.f};
            z = __builtin_amdgcn_mfma_f32_16x16x32_bf16(a0, qb0, z, 0, 0, 0);
            sc[tl] = __builtin_amdgcn_mfma_f32_16x16x32_bf16(a1, qb1, z, 0, 0, 0);
        }

        // ---- register softmax over 208 patches ----
        float mx = -FLT_MAX;
#pragma unroll
        for (int tl = 0; tl < 13; ++tl) {
            f32x4 bv = *(const f32x4*)&bias_s[tl * 16 + lg * 4];
#pragma unroll
            for (int r = 0; r < 4; ++r) {
                float sv = sc[tl][r] + bv[r];
                sc[tl][r] = sv;
                mx = fmaxf(mx, sv);
            }
        }
        mx = fmaxf(mx, __shfl_xor(mx, 16));
        mx = fmaxf(mx, __shfl_xor(mx, 32));
        float sum = 0.f;
        unsigned pk[14][2];
#pragma unroll
        for (int tl = 0; tl < 13; ++tl) {
            float e0 = __expf(sc[tl][0] - mx);
            float e1 = __expf(sc[tl][1] - mx);
            float e2 = __expf(sc[tl][2] - mx);
            float e3 = __expf(sc[tl][3] - mx);
            sum += (e0 + e1) + (e2 + e3);
            pk[tl][0] = pkbf(e0, e1);
            pk[tl][1] = pkbf(e2, e3);
        }
        pk[13][0] = 0u; pk[13][1] = 0u;
        sum += __shfl_xor(sum, 16);
        sum += __shfl_xor(sum, 32);
        float inv = 1.0f / sum;
        float li[4];
#pragma unroll
        for (int r = 0; r < 4; ++r) li[r] = __shfl(inv, lg * 4 + r);

        __syncthreads();  // all waves' QK reads of K done before Vt overwrites union

        // ---- load V (coalesced) and write V^T (pair-packed b32, swizzled) ----
        // unit: pp = patch-pair, d4 = 16B d-slice. g(row) = (row + 2*(row>>2)) & 7
#pragma unroll
        for (int u = 0; u < 7; ++u) {
            int unit = t + 256 * u;
            int pp = unit >> 4, d4 = unit & 15;
            int p0 = pp * 2;
            f32x4 va = {0.f, 0.f, 0.f, 0.f}, vb = {0.f, 0.f, 0.f, 0.f};
            if (p0 < LP) {
                const float* vg = v_g + ((kbase + p0) * HN + h) * DH + d4 * 4;
                va = *(const f32x4*)vg;
                vb = *(const f32x4*)(vg + (size_t)HN * DH);
            }
            int blk = p0 >> 3, sub = p0 & 7;
#pragma unroll
            for (int i = 0; i < 4; ++i) {
                int row = d4 * 4 + i;
                int g = (row + 2 * (row >> 2)) & 7;
                *(unsigned*)&KV_s[row * VST + (((blk ^ g) << 3) | sub)] = pkbf(va[i], vb[i]);
            }
        }
        __syncthreads();

        // ---- PV: A-fragments built in-register from pk via shfl_xor ----
        f32x4 pv[4];
#pragma unroll
        for (int dt = 0; dt < 4; ++dt) pv[dt] = (f32x4){0.f, 0.f, 0.f, 0.f};
#pragma unroll
        for (int ks = 0; ks < 7; ++ks) {
            unsigned a0 = pk[2 * ks][0],     a1 = pk[2 * ks][1];
            unsigned b0 = pk[2 * ks + 1][0], b1 = pk[2 * ks + 1][1];
            unsigned xA0 = __shfl_xor(a0, 16), xA1 = __shfl_xor(a1, 16);
            unsigned yA0 = __shfl_xor(a0, 32), yA1 = __shfl_xor(a1, 32);
            unsigned zA0 = __shfl_xor(a0, 48), zA1 = __shfl_xor(a1, 48);
            unsigned xB0 = __shfl_xor(b0, 16), xB1 = __shfl_xor(b1, 16);
            unsigned yB0 = __shfl_xor(b0, 32), yB1 = __shfl_xor(b1, 32);
            unsigned zB0 = __shfl_xor(b0, 48), zB1 = __shfl_xor(b1, 48);
            const bool lgb0 = (lg & 1) != 0, lgb1 = (lg >> 1) != 0;
            unsigned s0 = lgb1 ? (lgb0 ? xB0 : yB0) : (lgb0 ? zA0 : a0);
            unsigned s1 = lgb1 ? (lgb0 ? xB1 : yB1) : (lgb0 ? zA1 : a1);
            unsigned s2 = lgb1 ? (lgb0 ? b0 : zB0) : (lgb0 ? yA0 : xA0);
            unsigned s3 = lgb1 ? (lgb0 ? b1 : zB1) : (lgb0 ? yA1 : xA1);
            bf16x8 pa = __builtin_bit_cast(bf16x8, (u32x4){s0, s1, s2, s3});
#pragma unroll
            for (int dt = 0; dt < 4; ++dt) {
                int row = dt * 16 + lr;
                int g = (row + 2 * (row >> 2)) & 7;
                bf16x8 b = *(const bf16x8*)&KV_s[row * VST + ((((ks * 4 + lg) ^ g)) << 3)];
                pv[dt] = __builtin_amdgcn_mfma_f32_16x16x32_bf16(pa, b, pv[dt], 0, 0, 0);
            }
        }
#pragma unroll
        for (int dt = 0; dt < 4; ++dt)
#pragma unroll
            for (int r = 0; r < 4; ++r) mix[dt][r] += pv[dt][r] * li[r];
    }

    // ---- accumulate into mix[n][q = w*16 + lg*4 + r][h*64 + dt*16 + lr] ----
#pragma unroll
    for (int dt = 0; dt < 4; ++dt)
#pragma unroll
        for (int r = 0; r < 4; ++r)
            atomicAdd(mix_g + ((size_t)n * QN + w * 16 + lg * 4 + r) * EE + h * DH + dt * 16 + lr,
                      mix[dt][r]);
}

// ---------------------------------------------------------------------------
extern "C" void kernel_launch(void* const* d_in, const int* in_sizes, int n_in,
                              void* d_out, int out_size, void* d_ws, size_t ws_size,
                              hipStream_t stream) {
    const float* q  = (const float*)d_in[0];
    const float* k  = (const float*)d_in[1];
    const float* v  = (const float*)d_in[2];
    const int*   m  = (const int*)d_in[3];
    const float* Wi = (const float*)d_in[4];
    const float* Wo = (const float*)d_in[5];

    float* out = (float*)d_out;
    float* qs  = out + (size_t)N_B * QN * EE;  // second output (qs_out), also attn input
    float* mix = (float*)d_ws;                 // 2048x768 fp32 scratch (atomic-accumulated)

    const int mix_n4 = (N_B * QN * EE) / 4;
    dim3 ggrid((N_B * QN) / 64, EE / 48);
    gemm_mfma<<<ggrid, 256, 0, stream>>>(q, Wi, qs);                                 // in-proj
    zero_f32<<<(mix_n4 + 255) / 256, 256, 0, stream>>>(mix, mix_n4);                 // zero mix
    attn_mfma<<<dim3(HN, FN / FPB, N_B), 256, 0, stream>>>(qs, k, v, m, mix);        // attention
    gemm_mfma<<<ggrid, 256, 0, stream>>>(mix, Wo, out);                              // out-proj
}

// Round 8
// 240.554 us; speedup vs baseline: 1.3197x; 1.3197x over previous
//
#include <hip/hip_runtime.h>
#include <hip/hip_bf16.h>
#include <cfloat>

// dims
#define N_B 32
#define QN 64
#define FN 16
#define LP 196
#define HN 12
#define DH 64
#define EE 768
#define KLEN 3136
#define FPB 2          // frames per block (attn): 12*8*32 = 3072 blocks
#define KROWS 208      // padded patches per frame for QK (13*16)
#define VST 256        // Vt_s row stride in bf16 (512B, pow2 for XOR swizzle)

typedef short s16x4 __attribute__((ext_vector_type(4)));
typedef __bf16 bf16x8 __attribute__((ext_vector_type(8)));
typedef float f32x4 __attribute__((ext_vector_type(4)));
typedef unsigned u32x4 __attribute__((ext_vector_type(4)));

__device__ __forceinline__ bf16x8 cvt8(f32x4 a, f32x4 b) {
    bf16x8 r;
    r[0] = (__bf16)a[0]; r[1] = (__bf16)a[1]; r[2] = (__bf16)a[2]; r[3] = (__bf16)a[3];
    r[4] = (__bf16)b[0]; r[5] = (__bf16)b[1]; r[6] = (__bf16)b[2]; r[7] = (__bf16)b[3];
    return r;
}
__device__ __forceinline__ unsigned short bfb(float x) {
    return __builtin_bit_cast(unsigned short, (__bf16)x);
}
__device__ __forceinline__ unsigned pkbf(float lo, float hi) {
    return (unsigned)bfb(lo) | ((unsigned)bfb(hi) << 16);
}

// ---------------------------------------------------------------------------
// bf16 MFMA GEMM: C[m][n] = sum_k A[m][k] * W[n][k]  (fp32 in, fp32 out)
// ---------------------------------------------------------------------------
__global__ __launch_bounds__(256) void gemm_mfma(const float* __restrict__ A,
                                                 const float* __restrict__ W,
                                                 float* __restrict__ C) {
    __shared__ unsigned short As[64 * 72];
    __shared__ unsigned short Ws[48 * 72];
    const int t = threadIdx.x;
    const int w = t >> 6, lane = t & 63, lr = lane & 15, lg = lane >> 4;
    const int m0 = blockIdx.x * 64;
    const int n0 = blockIdx.y * 48;

    f32x4 acc[3];
#pragma unroll
    for (int ct = 0; ct < 3; ++ct) acc[ct] = (f32x4){0.f, 0.f, 0.f, 0.f};

    for (int k0 = 0; k0 < EE; k0 += 32) {
        {
            int row = t >> 2, cb = t & 3;
            const float* src = A + (size_t)(m0 + row) * EE + k0 + cb * 8;
            f32x4 a = *(const f32x4*)src, b = *(const f32x4*)(src + 4);
            *(bf16x8*)&As[row * 72 + cb * 8] = cvt8(a, b);
        }
        if (t < 192) {
            int row = t >> 2, cb = t & 3;
            const float* src = W + (size_t)(n0 + row) * EE + k0 + cb * 8;
            f32x4 a = *(const f32x4*)src, b = *(const f32x4*)(src + 4);
            *(bf16x8*)&Ws[row * 72 + cb * 8] = cvt8(a, b);
        }
        __syncthreads();
        bf16x8 a = *(const bf16x8*)&As[(w * 16 + lr) * 72 + lg * 8];
#pragma unroll
        for (int ct = 0; ct < 3; ++ct) {
            bf16x8 b = *(const bf16x8*)&Ws[(ct * 16 + lr) * 72 + lg * 8];
            acc[ct] = __builtin_amdgcn_mfma_f32_16x16x32_bf16(a, b, acc[ct], 0, 0, 0);
        }
        __syncthreads();
    }
#pragma unroll
    for (int ct = 0; ct < 3; ++ct)
#pragma unroll
        for (int r = 0; r < 4; ++r)
            C[(size_t)(m0 + w * 16 + lg * 4 + r) * EE + n0 + ct * 16 + lr] = acc[ct][r];
}

__global__ __launch_bounds__(256) void zero_f32(float* __restrict__ p, int n4) {
    int i = blockIdx.x * 256 + threadIdx.x;
    if (i < n4) ((float4*)p)[i] = make_float4(0.f, 0.f, 0.f, 0.f);
}

// ---------------------------------------------------------------------------
// MFMA attention, 33.8 KB LDS. Block = (h, frame-group, n); 4 waves; wave w
// owns queries [w*16, w*16+16). Per frame: K staged to swizzled [208][64]
// LDS; QK^T scores in regs (col=q); register softmax; P redistributed to PV
// A-fragments via in-register shfl_xor (no Pt LDS); V staged transposed
// (swizzled, stride 256); PV; atomicAdd into mix.
// launch_bounds floor (256,2): lets the allocator settle <=128 VGPR without
// forcing a 64-VGPR spill config (round-7 failure). LDS permits 4 blocks/CU.
// ---------------------------------------------------------------------------
__global__ __launch_bounds__(256, 2) void attn_mfma(const float* __restrict__ qs_g,
                                                    const float* __restrict__ k_g,
                                                    const float* __restrict__ v_g,
                                                    const int* __restrict__ m_g,
                                                    float* __restrict__ mix_g) {
    const int h = blockIdx.x, fg = blockIdx.y, n = blockIdx.z;

    __shared__ __attribute__((aligned(16))) unsigned short KV_s[64 * VST]; // K view: [208][64] swz; Vt view: [64][256] swz
    __shared__ __attribute__((aligned(16))) float bias_s[224];

    const int t = threadIdx.x;
    const int w = t >> 6, lane = t & 63, lr = lane & 15, lg = lane >> 4;

    // Q fragments straight to registers (scaled by d^-0.5)
    bf16x8 qb0, qb1;
    {
        const float* qp = qs_g + ((size_t)n * QN + w * 16 + lr) * EE + h * DH + lg * 8;
        f32x4 a = *(const f32x4*)qp, b = *(const f32x4*)(qp + 4);
        f32x4 c = *(const f32x4*)(qp + 32), d = *(const f32x4*)(qp + 36);
#pragma unroll
        for (int i = 0; i < 4; ++i) { a[i] *= 0.125f; b[i] *= 0.125f; c[i] *= 0.125f; d[i] *= 0.125f; }
        qb0 = cvt8(a, b);
        qb1 = cvt8(c, d);
    }

    float mix[4][4];
#pragma unroll
    for (int dt = 0; dt < 4; ++dt)
#pragma unroll
        for (int r = 0; r < 4; ++r) mix[dt][r] = 0.f;

    for (int ff = 0; ff < FPB; ++ff) {
        const size_t kbase = (size_t)n * KLEN + (size_t)(fg * FPB + ff) * LP;

        __syncthreads();  // prev-frame PV / softmax readers done before overwrite

        // ---- stage K [208][64] bf16, XOR-swizzled 16B blocks (g = p&7) ----
#pragma unroll
        for (int u = 0; u < 7; ++u) {
            int unit = t + 256 * u;
            if (unit < KROWS * 8) {
                int p = unit >> 3, blk = unit & 7;
                f32x4 a = {0.f, 0.f, 0.f, 0.f}, b = {0.f, 0.f, 0.f, 0.f};
                if (p < LP) {
                    const float* src = k_g + ((kbase + p) * HN + h) * DH + blk * 8;
                    a = *(const f32x4*)src;
                    b = *(const f32x4*)(src + 4);
                }
                *(bf16x8*)&KV_s[p * 64 + ((blk ^ (p & 7)) << 3)] = cvt8(a, b);
            }
        }
        if (t < 224) {
            float bv = -1e30f;
            if (t < LP && m_g[kbase + t] != 0) bv = 0.f;
            bias_s[t] = bv;
        }
        __syncthreads();

        // ---- QK^T: lane holds scores for q = w*16+lr, p = tl*16 + lg*4 + r ----
        f32x4 sc[13];
#pragma unroll
        for (int tl = 0; tl < 13; ++tl) {
            int row = tl * 16 + lr;
            bf16x8 a0 = *(const bf16x8*)&KV_s[row * 64 + ((lg ^ (lr & 7)) << 3)];
            bf16x8 a1 = *(const bf16x8*)&KV_s[row * 64 + (((4 + lg) ^ (lr & 7)) << 3)];
            f32x4 z = {0.f, 0.f, 0.f, 0.f};
            z = __builtin_amdgcn_mfma_f32_16x16x32_bf16(a0, qb0, z, 0, 0, 0);
            sc[tl] = __builtin_amdgcn_mfma_f32_16x16x32_bf16(a1, qb1, z, 0, 0, 0);
        }

        // ---- register softmax over 208 patches ----
        float mx = -FLT_MAX;
#pragma unroll
        for (int tl = 0; tl < 13; ++tl) {
            f32x4 bv = *(const f32x4*)&bias_s[tl * 16 + lg * 4];
#pragma unroll
            for (int r = 0; r < 4; ++r) {
                float sv = sc[tl][r] + bv[r];
                sc[tl][r] = sv;
                mx = fmaxf(mx, sv);
            }
        }
        mx = fmaxf(mx, __shfl_xor(mx, 16));
        mx = fmaxf(mx, __shfl_xor(mx, 32));
        float sum = 0.f;
        unsigned pk[14][2];
#pragma unroll
        for (int tl = 0; tl < 13; ++tl) {
            float e0 = __expf(sc[tl][0] - mx);
            float e1 = __expf(sc[tl][1] - mx);
            float e2 = __expf(sc[tl][2] - mx);
            float e3 = __expf(sc[tl][3] - mx);
            sum += (e0 + e1) + (e2 + e3);
            pk[tl][0] = pkbf(e0, e1);
            pk[tl][1] = pkbf(e2, e3);
        }
        pk[13][0] = 0u; pk[13][1] = 0u;
        sum += __shfl_xor(sum, 16);
        sum += __shfl_xor(sum, 32);
        float inv = 1.0f / sum;
        float li[4];
#pragma unroll
        for (int r = 0; r < 4; ++r) li[r] = __shfl(inv, lg * 4 + r);

        __syncthreads();  // all waves' QK reads of K done before Vt overwrites union

        // ---- load V (coalesced) and write V^T (pair-packed b32, swizzled) ----
        // unit: pp = patch-pair, d4 = 16B d-slice. g(row) = (row + 2*(row>>2)) & 7
#pragma unroll
        for (int u = 0; u < 7; ++u) {
            int unit = t + 256 * u;
            int pp = unit >> 4, d4 = unit & 15;
            int p0 = pp * 2;
            f32x4 va = {0.f, 0.f, 0.f, 0.f}, vb = {0.f, 0.f, 0.f, 0.f};
            if (p0 < LP) {
                const float* vg = v_g + ((kbase + p0) * HN + h) * DH + d4 * 4;
                va = *(const f32x4*)vg;
                if (p0 + 1 < LP) vb = *(const f32x4*)(vg + (size_t)HN * DH);
            }
            int blk = p0 >> 3, sub = p0 & 7;
#pragma unroll
            for (int i = 0; i < 4; ++i) {
                int row = d4 * 4 + i;
                int g = (row + 2 * (row >> 2)) & 7;
                *(unsigned*)&KV_s[row * VST + (((blk ^ g) << 3) | sub)] = pkbf(va[i], vb[i]);
            }
        }
        __syncthreads();

        // ---- PV: A-fragments built in-register from pk via shfl_xor ----
        f32x4 pv[4];
#pragma unroll
        for (int dt = 0; dt < 4; ++dt) pv[dt] = (f32x4){0.f, 0.f, 0.f, 0.f};
        const bool lgb0 = (lg & 1) != 0, lgb1 = (lg >> 1) != 0;
#pragma unroll
        for (int ks = 0; ks < 7; ++ks) {
            unsigned a0 = pk[2 * ks][0],     a1 = pk[2 * ks][1];
            unsigned b0 = pk[2 * ks + 1][0], b1 = pk[2 * ks + 1][1];
            unsigned xA0 = __shfl_xor(a0, 16), xA1 = __shfl_xor(a1, 16);
            unsigned yA0 = __shfl_xor(a0, 32), yA1 = __shfl_xor(a1, 32);
            unsigned zA0 = __shfl_xor(a0, 48), zA1 = __shfl_xor(a1, 48);
            unsigned xB0 = __shfl_xor(b0, 16), xB1 = __shfl_xor(b1, 16);
            unsigned yB0 = __shfl_xor(b0, 32), yB1 = __shfl_xor(b1, 32);
            unsigned zB0 = __shfl_xor(b0, 48), zB1 = __shfl_xor(b1, 48);
            unsigned s0 = lgb1 ? (lgb0 ? xB0 : yB0) : (lgb0 ? zA0 : a0);
            unsigned s1 = lgb1 ? (lgb0 ? xB1 : yB1) : (lgb0 ? zA1 : a1);
            unsigned s2 = lgb1 ? (lgb0 ? b0 : zB0) : (lgb0 ? yA0 : xA0);
            unsigned s3 = lgb1 ? (lgb0 ? b1 : zB1) : (lgb0 ? yA1 : xA1);
            bf16x8 pa = __builtin_bit_cast(bf16x8, (u32x4){s0, s1, s2, s3});
#pragma unroll
            for (int dt = 0; dt < 4; ++dt) {
                int row = dt * 16 + lr;
                int g = (row + 2 * (row >> 2)) & 7;
                bf16x8 b = *(const bf16x8*)&KV_s[row * VST + ((((ks * 4 + lg) ^ g)) << 3)];
                pv[dt] = __builtin_amdgcn_mfma_f32_16x16x32_bf16(pa, b, pv[dt], 0, 0, 0);
            }
        }
#pragma unroll
        for (int dt = 0; dt < 4; ++dt)
#pragma unroll
            for (int r = 0; r < 4; ++r) mix[dt][r] += pv[dt][r] * li[r];
    }

    // ---- accumulate into mix[n][q = w*16 + lg*4 + r][h*64 + dt*16 + lr] ----
#pragma unroll
    for (int dt = 0; dt < 4; ++dt)
#pragma unroll
        for (int r = 0; r < 4; ++r)
            atomicAdd(mix_g + ((size_t)n * QN + w * 16 + lg * 4 + r) * EE + h * DH + dt * 16 + lr,
                      mix[dt][r]);
}

// ---------------------------------------------------------------------------
extern "C" void kernel_launch(void* const* d_in, const int* in_sizes, int n_in,
                              void* d_out, int out_size, void* d_ws, size_t ws_size,
                              hipStream_t stream) {
    const float* q  = (const float*)d_in[0];
    const float* k  = (const float*)d_in[1];
    const float* v  = (const float*)d_in[2];
    const int*   m  = (const int*)d_in[3];
    const float* Wi = (const float*)d_in[4];
    const float* Wo = (const float*)d_in[5];

    float* out = (float*)d_out;
    float* qs  = out + (size_t)N_B * QN * EE;  // second output (qs_out), also attn input
    float* mix = (float*)d_ws;                 // 2048x768 fp32 scratch (atomic-accumulated)

    const int mix_n4 = (N_B * QN * EE) / 4;
    dim3 ggrid((N_B * QN) / 64, EE / 48);
    gemm_mfma<<<ggrid, 256, 0, stream>>>(q, Wi, qs);                                 // in-proj
    zero_f32<<<(mix_n4 + 255) / 256, 256, 0, stream>>>(mix, mix_n4);                 // zero mix
    attn_mfma<<<dim3(HN, FN / FPB, N_B), 256, 0, stream>>>(qs, k, v, m, mix);        // attention
    gemm_mfma<<<ggrid, 256, 0, stream>>>(mix, Wo, out);                              // out-proj
}

// Round 10
// 217.988 us; speedup vs baseline: 1.4563x; 1.1035x over previous
//
#include <hip/hip_runtime.h>
#include <hip/hip_bf16.h>
#include <cfloat>

// dims
#define N_B 32
#define QN 64
#define FN 16
#define LP 196
#define HN 12
#define DH 64
#define EE 768
#define KLEN 3136
#define FPB 2          // frames per block (attn): 12*8*32 = 3072 blocks = 3 rounds of 4/CU
#define KROWS 208      // padded patches per frame for QK (13*16)
#define VST 256        // Vt_s row stride in bf16 (512B, pow2 for XOR swizzle)

typedef short s16x4 __attribute__((ext_vector_type(4)));
typedef __bf16 bf16x4 __attribute__((ext_vector_type(4)));
typedef __bf16 bf16x8 __attribute__((ext_vector_type(8)));
typedef float f32x4 __attribute__((ext_vector_type(4)));
typedef unsigned u32x2 __attribute__((ext_vector_type(2)));

__device__ __forceinline__ bf16x8 cvt8(f32x4 a, f32x4 b) {
    bf16x8 r;
    r[0] = (__bf16)a[0]; r[1] = (__bf16)a[1]; r[2] = (__bf16)a[2]; r[3] = (__bf16)a[3];
    r[4] = (__bf16)b[0]; r[5] = (__bf16)b[1]; r[6] = (__bf16)b[2]; r[7] = (__bf16)b[3];
    return r;
}
__device__ __forceinline__ unsigned short bfb(float x) {
    return __builtin_bit_cast(unsigned short, (__bf16)x);
}
__device__ __forceinline__ unsigned pkbf(float lo, float hi) {
    return (unsigned)bfb(lo) | ((unsigned)bfb(hi) << 16);
}

// 16x16x16 bf16 MFMA with name-portability fallback
__device__ __forceinline__ f32x4 mfma16(s16x4 a, s16x4 b, f32x4 c) {
#if __has_builtin(__builtin_amdgcn_mfma_f32_16x16x16_bf16)
    return __builtin_amdgcn_mfma_f32_16x16x16_bf16(__builtin_bit_cast(bf16x4, a),
                                                   __builtin_bit_cast(bf16x4, b), c, 0, 0, 0);
#elif __has_builtin(__builtin_amdgcn_mfma_f32_16x16x16bf16_1k)
    return __builtin_amdgcn_mfma_f32_16x16x16bf16_1k(a, b, c, 0, 0, 0);
#else
    f32x4 d;
    asm volatile("v_mfma_f32_16x16x16_bf16 %0, %1, %2, %3"
                 : "=v"(d) : "v"(a), "v"(b), "v"(c));
    return d;
#endif
}

// ---------------------------------------------------------------------------
// bf16 MFMA GEMM: C[m][n] = sum_k A[m][k] * W[n][k]  (fp32 in, fp32 out)
// ---------------------------------------------------------------------------
__global__ __launch_bounds__(256) void gemm_mfma(const float* __restrict__ A,
                                                 const float* __restrict__ W,
                                                 float* __restrict__ C) {
    __shared__ unsigned short As[64 * 72];
    __shared__ unsigned short Ws[48 * 72];
    const int t = threadIdx.x;
    const int w = t >> 6, lane = t & 63, lr = lane & 15, lg = lane >> 4;
    const int m0 = blockIdx.x * 64;
    const int n0 = blockIdx.y * 48;

    f32x4 acc[3];
#pragma unroll
    for (int ct = 0; ct < 3; ++ct) acc[ct] = (f32x4){0.f, 0.f, 0.f, 0.f};

    for (int k0 = 0; k0 < EE; k0 += 32) {
        {
            int row = t >> 2, cb = t & 3;
            const float* src = A + (size_t)(m0 + row) * EE + k0 + cb * 8;
            f32x4 a = *(const f32x4*)src, b = *(const f32x4*)(src + 4);
            *(bf16x8*)&As[row * 72 + cb * 8] = cvt8(a, b);
        }
        if (t < 192) {
            int row = t >> 2, cb = t & 3;
            const float* src = W + (size_t)(n0 + row) * EE + k0 + cb * 8;
            f32x4 a = *(const f32x4*)src, b = *(const f32x4*)(src + 4);
            *(bf16x8*)&Ws[row * 72 + cb * 8] = cvt8(a, b);
        }
        __syncthreads();
        bf16x8 a = *(const bf16x8*)&As[(w * 16 + lr) * 72 + lg * 8];
#pragma unroll
        for (int ct = 0; ct < 3; ++ct) {
            bf16x8 b = *(const bf16x8*)&Ws[(ct * 16 + lr) * 72 + lg * 8];
            acc[ct] = __builtin_amdgcn_mfma_f32_16x16x32_bf16(a, b, acc[ct], 0, 0, 0);
        }
        __syncthreads();
    }
#pragma unroll
    for (int ct = 0; ct < 3; ++ct)
#pragma unroll
        for (int r = 0; r < 4; ++r)
            C[(size_t)(m0 + w * 16 + lg * 4 + r) * EE + n0 + ct * 16 + lr] = acc[ct][r];
}

__global__ __launch_bounds__(256) void zero_f32(float* __restrict__ p, int n4) {
    int i = blockIdx.x * 256 + threadIdx.x;
    if (i < n4) ((float4*)p)[i] = make_float4(0.f, 0.f, 0.f, 0.f);
}

// ---------------------------------------------------------------------------
// MFMA attention v3.1, 33.7 KB LDS (4 blocks/CU). Block = (h, frame-group, n);
// 4 waves; wave w owns queries [w*16, w*16+16).
// QK^T (16x16x32, swapped) -> scores in regs (p=tl*16+lg*4+r, q=lr) ->
// register softmax -> pk bf16 pairs == PV A-fragments for 16x16x16 MFMA
// (zero data movement) -> PV over swizzled Vt in two d-halves with V loads
// double-batched. v3.1 fix: Vt pad columns [196,208) are zero-WRITTEN
// (write guard p0<KROWS, load guard p0<LP) — r9 left them as garbage and
// 0*garbage produced NaN via Inf/NaN bf16 patterns in uninit LDS.
// ---------------------------------------------------------------------------
__global__ __launch_bounds__(256, 2) void attn_mfma(const float* __restrict__ qs_g,
                                                    const float* __restrict__ k_g,
                                                    const float* __restrict__ v_g,
                                                    const int* __restrict__ m_g,
                                                    float* __restrict__ mix_g) {
    const int h = blockIdx.x, fg = blockIdx.y, n = blockIdx.z;

    __shared__ __attribute__((aligned(16))) unsigned short KV_s[64 * VST]; // K view: [208][64] swz; Vt view: [64][256] swz
    __shared__ __attribute__((aligned(16))) float bias_s[224];

    const int t = threadIdx.x;
    const int w = t >> 6, lane = t & 63, lr = lane & 15, lg = lane >> 4;

    // Q fragments straight to registers (scaled by d^-0.5)
    bf16x8 qb0, qb1;
    {
        const float* qp = qs_g + ((size_t)n * QN + w * 16 + lr) * EE + h * DH + lg * 8;
        f32x4 a = *(const f32x4*)qp, b = *(const f32x4*)(qp + 4);
        f32x4 c = *(const f32x4*)(qp + 32), d = *(const f32x4*)(qp + 36);
#pragma unroll
        for (int i = 0; i < 4; ++i) { a[i] *= 0.125f; b[i] *= 0.125f; c[i] *= 0.125f; d[i] *= 0.125f; }
        qb0 = cvt8(a, b);
        qb1 = cvt8(c, d);
    }

    float mix[4][4];
#pragma unroll
    for (int dt = 0; dt < 4; ++dt)
#pragma unroll
        for (int r = 0; r < 4; ++r) mix[dt][r] = 0.f;

    for (int ff = 0; ff < FPB; ++ff) {
        const size_t kbase = (size_t)n * KLEN + (size_t)(fg * FPB + ff) * LP;

        __syncthreads();  // B0: prev-frame PV readers done before K overwrite

        // ---- stage K [208][64] bf16, XOR-swizzled 16B blocks (g = p&7) ----
#pragma unroll
        for (int u = 0; u < 7; ++u) {
            int unit = t + 256 * u;
            if (unit < KROWS * 8) {
                int p = unit >> 3, blk = unit & 7;
                f32x4 a = {0.f, 0.f, 0.f, 0.f}, b = {0.f, 0.f, 0.f, 0.f};
                if (p < LP) {
                    const float* src = k_g + ((kbase + p) * HN + h) * DH + blk * 8;
                    a = *(const f32x4*)src;
                    b = *(const f32x4*)(src + 4);
                }
                *(bf16x8*)&KV_s[p * 64 + ((blk ^ (p & 7)) << 3)] = cvt8(a, b);
            }
        }
        if (t < 224) {
            float bv = -1e30f;
            if (t < LP && m_g[kbase + t] != 0) bv = 0.f;
            bias_s[t] = bv;
        }
        __syncthreads();  // B1: K + bias visible

        // ---- QK^T: lane holds scores for q = w*16+lr, p = tl*16 + lg*4 + r ----
        f32x4 sc[13];
        __builtin_amdgcn_s_setprio(1);
#pragma unroll
        for (int tl = 0; tl < 13; ++tl) {
            int row = tl * 16 + lr;
            bf16x8 a0 = *(const bf16x8*)&KV_s[row * 64 + ((lg ^ (lr & 7)) << 3)];
            bf16x8 a1 = *(const bf16x8*)&KV_s[row * 64 + (((4 + lg) ^ (lr & 7)) << 3)];
            f32x4 z = {0.f, 0.f, 0.f, 0.f};
            z = __builtin_amdgcn_mfma_f32_16x16x32_bf16(a0, qb0, z, 0, 0, 0);
            sc[tl] = __builtin_amdgcn_mfma_f32_16x16x32_bf16(a1, qb1, z, 0, 0, 0);
        }
        __builtin_amdgcn_s_setprio(0);

        // ---- issue V batch1 loads (d in [0,32)): pairs x 8 d-slices ----
        f32x4 va[4], vb[4];
#pragma unroll
        for (int u = 0; u < 4; ++u) {
            int unit = t + 256 * u;
            int pp = unit >> 3, d4 = unit & 7;
            int p0 = pp * 2;
            va[u] = (f32x4){0.f, 0.f, 0.f, 0.f};
            vb[u] = (f32x4){0.f, 0.f, 0.f, 0.f};
            if (p0 < LP) {
                const float* vg = v_g + ((kbase + p0) * HN + h) * DH + d4 * 4;
                va[u] = *(const f32x4*)vg;
                if (p0 + 1 < LP) vb[u] = *(const f32x4*)(vg + (size_t)HN * DH);
            }
        }

        // ---- register softmax over 208 patches ----
        float mx = -FLT_MAX;
#pragma unroll
        for (int tl = 0; tl < 13; ++tl) {
            f32x4 bv = *(const f32x4*)&bias_s[tl * 16 + lg * 4];
#pragma unroll
            for (int r = 0; r < 4; ++r) {
                float sv = sc[tl][r] + bv[r];
                sc[tl][r] = sv;
                mx = fmaxf(mx, sv);
            }
        }
        mx = fmaxf(mx, __shfl_xor(mx, 16));
        mx = fmaxf(mx, __shfl_xor(mx, 32));
        float sum = 0.f;
        unsigned pk[13][2];
#pragma unroll
        for (int tl = 0; tl < 13; ++tl) {
            float e0 = __expf(sc[tl][0] - mx);
            float e1 = __expf(sc[tl][1] - mx);
            float e2 = __expf(sc[tl][2] - mx);
            float e3 = __expf(sc[tl][3] - mx);
            sum += (e0 + e1) + (e2 + e3);
            pk[tl][0] = pkbf(e0, e1);
            pk[tl][1] = pkbf(e2, e3);
        }
        sum += __shfl_xor(sum, 16);
        sum += __shfl_xor(sum, 32);
        float inv = 1.0f / sum;
        float li[4];
#pragma unroll
        for (int r = 0; r < 4; ++r) li[r] = __shfl(inv, lg * 4 + r);

        __syncthreads();  // B2: all waves' QK reads of K done

        // ---- write Vt batch1 (rows 0..31), swizzled g(row)=(row+2*(row>>2))&7 ----
        // write guard p0 < KROWS: pad pairs [196,208) get explicit zeros
#pragma unroll
        for (int u = 0; u < 4; ++u) {
            int unit = t + 256 * u;
            int pp = unit >> 3, d4 = unit & 7;
            int p0 = pp * 2;
            if (p0 < KROWS) {
                int blk = p0 >> 3, sub = p0 & 7;
#pragma unroll
                for (int i = 0; i < 4; ++i) {
                    int row = d4 * 4 + i;
                    int g = (row + 2 * (row >> 2)) & 7;
                    *(unsigned*)&KV_s[row * VST + (((blk ^ g) << 3) | sub)] = pkbf(va[u][i], vb[u][i]);
                }
            }
        }
        // ---- issue V batch2 loads (d in [32,64)) — hidden under PV dt=0,1 ----
#pragma unroll
        for (int u = 0; u < 4; ++u) {
            int unit = t + 256 * u;
            int pp = unit >> 3, d4 = unit & 7;
            int p0 = pp * 2;
            va[u] = (f32x4){0.f, 0.f, 0.f, 0.f};
            vb[u] = (f32x4){0.f, 0.f, 0.f, 0.f};
            if (p0 < LP) {
                const float* vg = v_g + ((kbase + p0) * HN + h) * DH + (8 + d4) * 4;
                va[u] = *(const f32x4*)vg;
                if (p0 + 1 < LP) vb[u] = *(const f32x4*)(vg + (size_t)HN * DH);
            }
        }
        __syncthreads();  // B3: Vt rows 0..31 visible

        // ---- PV dt=0,1: A = pk fragments directly (16x16x16) ----
        f32x4 pv[4];
#pragma unroll
        for (int dt = 0; dt < 4; ++dt) pv[dt] = (f32x4){0.f, 0.f, 0.f, 0.f};
        __builtin_amdgcn_s_setprio(1);
#pragma unroll
        for (int dt = 0; dt < 2; ++dt) {
            int row = dt * 16 + lr;
            int g = (row + 2 * (row >> 2)) & 7;
#pragma unroll
            for (int kt = 0; kt < 13; ++kt) {
                int c0 = kt * 16 + lg * 4;
                s16x4 b = *(const s16x4*)&KV_s[row * VST + ((((c0 >> 3) ^ g) << 3) | (c0 & 7))];
                s16x4 a = __builtin_bit_cast(s16x4, (u32x2){pk[kt][0], pk[kt][1]});
                pv[dt] = mfma16(a, b, pv[dt]);
            }
        }
        __builtin_amdgcn_s_setprio(0);

        // ---- write Vt batch2 (rows 32..63; K rows 128..207 dead since B2) ----
#pragma unroll
        for (int u = 0; u < 4; ++u) {
            int unit = t + 256 * u;
            int pp = unit >> 3, d4 = unit & 7;
            int p0 = pp * 2;
            if (p0 < KROWS) {
                int blk = p0 >> 3, sub = p0 & 7;
#pragma unroll
                for (int i = 0; i < 4; ++i) {
                    int row = 32 + d4 * 4 + i;
                    int g = (row + 2 * (row >> 2)) & 7;
                    *(unsigned*)&KV_s[row * VST + (((blk ^ g) << 3) | sub)] = pkbf(va[u][i], vb[u][i]);
                }
            }
        }
        __syncthreads();  // B4: Vt rows 32..63 visible

        // ---- PV dt=2,3 ----
        __builtin_amdgcn_s_setprio(1);
#pragma unroll
        for (int dt = 2; dt < 4; ++dt) {
            int row = dt * 16 + lr;
            int g = (row + 2 * (row >> 2)) & 7;
#pragma unroll
            for (int kt = 0; kt < 13; ++kt) {
                int c0 = kt * 16 + lg * 4;
                s16x4 b = *(const s16x4*)&KV_s[row * VST + ((((c0 >> 3) ^ g) << 3) | (c0 & 7))];
                s16x4 a = __builtin_bit_cast(s16x4, (u32x2){pk[kt][0], pk[kt][1]});
                pv[dt] = mfma16(a, b, pv[dt]);
            }
        }
        __builtin_amdgcn_s_setprio(0);

#pragma unroll
        for (int dt = 0; dt < 4; ++dt)
#pragma unroll
            for (int r = 0; r < 4; ++r) mix[dt][r] += pv[dt][r] * li[r];
    }

    // ---- accumulate into mix[n][q = w*16 + lg*4 + r][h*64 + dt*16 + lr] ----
#pragma unroll
    for (int dt = 0; dt < 4; ++dt)
#pragma unroll
        for (int r = 0; r < 4; ++r)
            atomicAdd(mix_g + ((size_t)n * QN + w * 16 + lg * 4 + r) * EE + h * DH + dt * 16 + lr,
                      mix[dt][r]);
}

// ---------------------------------------------------------------------------
extern "C" void kernel_launch(void* const* d_in, const int* in_sizes, int n_in,
                              void* d_out, int out_size, void* d_ws, size_t ws_size,
                              hipStream_t stream) {
    const float* q  = (const float*)d_in[0];
    const float* k  = (const float*)d_in[1];
    const float* v  = (const float*)d_in[2];
    const int*   m  = (const int*)d_in[3];
    const float* Wi = (const float*)d_in[4];
    const float* Wo = (const float*)d_in[5];

    float* out = (float*)d_out;
    float* qs  = out + (size_t)N_B * QN * EE;  // second output (qs_out), also attn input
    float* mix = (float*)d_ws;                 // 2048x768 fp32 scratch (atomic-accumulated)

    const int mix_n4 = (N_B * QN * EE) / 4;
    dim3 ggrid((N_B * QN) / 64, EE / 48);
    gemm_mfma<<<ggrid, 256, 0, stream>>>(q, Wi, qs);                                 // in-proj
    zero_f32<<<(mix_n4 + 255) / 256, 256, 0, stream>>>(mix, mix_n4);                 // zero mix
    attn_mfma<<<dim3(HN, FN / FPB, N_B), 256, 0, stream>>>(qs, k, v, m, mix);        // attention
    gemm_mfma<<<ggrid, 256, 0, stream>>>(mix, Wo, out);                              // out-proj
}

// Round 11
// 207.010 us; speedup vs baseline: 1.5335x; 1.0530x over previous
//
#include <hip/hip_runtime.h>
#include <hip/hip_bf16.h>
#include <cfloat>

// dims
#define N_B 32
#define QN 64
#define FN 16
#define LP 196
#define HN 12
#define DH 64
#define EE 768
#define KLEN 3136
#define FPB 2          // frames per block (attn): 12*8*32 = 3072 blocks
#define KROWS 208      // padded patches per frame for QK (13*16)
#define VST 256        // Vt_s row stride in bf16 (512B, pow2 for XOR swizzle)

typedef short s16x4 __attribute__((ext_vector_type(4)));
typedef __bf16 bf16x4 __attribute__((ext_vector_type(4)));
typedef __bf16 bf16x8 __attribute__((ext_vector_type(8)));
typedef float f32x4 __attribute__((ext_vector_type(4)));
typedef unsigned u32x2 __attribute__((ext_vector_type(2)));

__device__ __forceinline__ bf16x8 cvt8(f32x4 a, f32x4 b) {
    bf16x8 r;
    r[0] = (__bf16)a[0]; r[1] = (__bf16)a[1]; r[2] = (__bf16)a[2]; r[3] = (__bf16)a[3];
    r[4] = (__bf16)b[0]; r[5] = (__bf16)b[1]; r[6] = (__bf16)b[2]; r[7] = (__bf16)b[3];
    return r;
}
__device__ __forceinline__ unsigned short bfb(float x) {
    return __builtin_bit_cast(unsigned short, (__bf16)x);
}
__device__ __forceinline__ unsigned pkbf(float lo, float hi) {
    return (unsigned)bfb(lo) | ((unsigned)bfb(hi) << 16);
}

// 16x16x16 bf16 MFMA with name-portability fallback
__device__ __forceinline__ f32x4 mfma16(s16x4 a, s16x4 b, f32x4 c) {
#if __has_builtin(__builtin_amdgcn_mfma_f32_16x16x16_bf16)
    return __builtin_amdgcn_mfma_f32_16x16x16_bf16(__builtin_bit_cast(bf16x4, a),
                                                   __builtin_bit_cast(bf16x4, b), c, 0, 0, 0);
#elif __has_builtin(__builtin_amdgcn_mfma_f32_16x16x16bf16_1k)
    return __builtin_amdgcn_mfma_f32_16x16x16bf16_1k(a, b, c, 0, 0, 0);
#else
    f32x4 d;
    asm volatile("v_mfma_f32_16x16x16_bf16 %0, %1, %2, %3"
                 : "=v"(d) : "v"(a), "v"(b), "v"(c));
    return d;
#endif
}

// ---------------------------------------------------------------------------
// bf16 MFMA GEMM: C[m][n] = sum_k A[m][k] * W[n][k]  (fp32 in, fp32 out)
// ---------------------------------------------------------------------------
__global__ __launch_bounds__(256) void gemm_mfma(const float* __restrict__ A,
                                                 const float* __restrict__ W,
                                                 float* __restrict__ C) {
    __shared__ unsigned short As[64 * 72];
    __shared__ unsigned short Ws[48 * 72];
    const int t = threadIdx.x;
    const int w = t >> 6, lane = t & 63, lr = lane & 15, lg = lane >> 4;
    const int m0 = blockIdx.x * 64;
    const int n0 = blockIdx.y * 48;

    f32x4 acc[3];
#pragma unroll
    for (int ct = 0; ct < 3; ++ct) acc[ct] = (f32x4){0.f, 0.f, 0.f, 0.f};

    for (int k0 = 0; k0 < EE; k0 += 32) {
        {
            int row = t >> 2, cb = t & 3;
            const float* src = A + (size_t)(m0 + row) * EE + k0 + cb * 8;
            f32x4 a = *(const f32x4*)src, b = *(const f32x4*)(src + 4);
            *(bf16x8*)&As[row * 72 + cb * 8] = cvt8(a, b);
        }
        if (t < 192) {
            int row = t >> 2, cb = t & 3;
            const float* src = W + (size_t)(n0 + row) * EE + k0 + cb * 8;
            f32x4 a = *(const f32x4*)src, b = *(const f32x4*)(src + 4);
            *(bf16x8*)&Ws[row * 72 + cb * 8] = cvt8(a, b);
        }
        __syncthreads();
        bf16x8 a = *(const bf16x8*)&As[(w * 16 + lr) * 72 + lg * 8];
#pragma unroll
        for (int ct = 0; ct < 3; ++ct) {
            bf16x8 b = *(const bf16x8*)&Ws[(ct * 16 + lr) * 72 + lg * 8];
            acc[ct] = __builtin_amdgcn_mfma_f32_16x16x32_bf16(a, b, acc[ct], 0, 0, 0);
        }
        __syncthreads();
    }
#pragma unroll
    for (int ct = 0; ct < 3; ++ct)
#pragma unroll
        for (int r = 0; r < 4; ++r)
            C[(size_t)(m0 + w * 16 + lg * 4 + r) * EE + n0 + ct * 16 + lr] = acc[ct][r];
}

__global__ __launch_bounds__(256) void zero_f32(float* __restrict__ p, int n4) {
    int i = blockIdx.x * 256 + threadIdx.x;
    if (i < n4) ((float4*)p)[i] = make_float4(0.f, 0.f, 0.f, 0.f);
}

// ---------------------------------------------------------------------------
// MFMA attention v4: 2-barrier frame. Block = (h, frame-group, n); 4 waves;
// wave w owns queries [w*16, w*16+16). Per frame:
//   B0 -> stage K (swizzled [208][64]) + stage Vt (g-swizzled [64][256],
//   transpose-written from coalesced loads) + bias, all global loads issued
//   back-to-back at frame start -> B1 -> QK^T (swapped, 16x16x32) ->
//   register softmax (inv folded into pk = P/sum in bf16) -> PV via
//   16x16x16 MFMA with pk as A-fragment and mix[] as the C accumulator.
// No Pt buffer, no mid-frame barriers, no li shuffles, no pv temp.
// ---------------------------------------------------------------------------
__global__ __launch_bounds__(256, 2) void attn_mfma(const float* __restrict__ qs_g,
                                                    const float* __restrict__ k_g,
                                                    const float* __restrict__ v_g,
                                                    const int* __restrict__ m_g,
                                                    float* __restrict__ mix_g) {
    const int h = blockIdx.x, fg = blockIdx.y, n = blockIdx.z;

    __shared__ __attribute__((aligned(16))) unsigned short K_s[KROWS * 64];  // [208][64] swz
    __shared__ __attribute__((aligned(16))) unsigned short Vt_s[64 * VST];   // [64][256] swz
    __shared__ __attribute__((aligned(16))) float bias_s[224];

    const int t = threadIdx.x;
    const int w = t >> 6, lane = t & 63, lr = lane & 15, lg = lane >> 4;

    // Q fragments straight to registers (scaled by d^-0.5)
    bf16x8 qb0, qb1;
    {
        const float* qp = qs_g + ((size_t)n * QN + w * 16 + lr) * EE + h * DH + lg * 8;
        f32x4 a = *(const f32x4*)qp, b = *(const f32x4*)(qp + 4);
        f32x4 c = *(const f32x4*)(qp + 32), d = *(const f32x4*)(qp + 36);
#pragma unroll
        for (int i = 0; i < 4; ++i) { a[i] *= 0.125f; b[i] *= 0.125f; c[i] *= 0.125f; d[i] *= 0.125f; }
        qb0 = cvt8(a, b);
        qb1 = cvt8(c, d);
    }

    float mix[4][4];  // PV accumulator across kt AND frames (inv pre-folded into pk)
#pragma unroll
    for (int dt = 0; dt < 4; ++dt)
#pragma unroll
        for (int r = 0; r < 4; ++r) mix[dt][r] = 0.f;

    for (int ff = 0; ff < FPB; ++ff) {
        const size_t kbase = (size_t)n * KLEN + (size_t)(fg * FPB + ff) * LP;

        __syncthreads();  // B0: prev frame fully consumed (PV reads of Vt done)

        // ---- issue K loads (7 units x 32B, coalesced) ----
        f32x4 ka[7], kb[7];
#pragma unroll
        for (int u = 0; u < 7; ++u) {
            int unit = t + 256 * u;
            int p = unit >> 3, blk = unit & 7;
            ka[u] = (f32x4){0.f, 0.f, 0.f, 0.f};
            kb[u] = (f32x4){0.f, 0.f, 0.f, 0.f};
            if (unit < KROWS * 8 && p < LP) {
                const float* src = k_g + ((kbase + p) * HN + h) * DH + blk * 8;
                ka[u] = *(const f32x4*)src;
                kb[u] = *(const f32x4*)(src + 4);
            }
        }
        // ---- issue V loads (7 units x 32B, coalesced: 16 lanes x 16B) ----
        f32x4 va[7], vb[7];
#pragma unroll
        for (int u = 0; u < 7; ++u) {
            int unit = t + 256 * u;
            int pp = unit >> 4, d4 = unit & 15;
            int p0 = pp * 2;
            va[u] = (f32x4){0.f, 0.f, 0.f, 0.f};
            vb[u] = (f32x4){0.f, 0.f, 0.f, 0.f};
            if (p0 < LP) {
                const float* vg = v_g + ((kbase + p0) * HN + h) * DH + d4 * 4;
                va[u] = *(const f32x4*)vg;
                if (p0 + 1 < LP) vb[u] = *(const f32x4*)(vg + (size_t)HN * DH);
            }
        }
        int mr = (t < LP) ? m_g[kbase + t] : 0;

        // ---- write K [208][64] bf16, XOR-swizzled 16B blocks (g = p&7) ----
#pragma unroll
        for (int u = 0; u < 7; ++u) {
            int unit = t + 256 * u;
            if (unit < KROWS * 8) {
                int p = unit >> 3, blk = unit & 7;
                *(bf16x8*)&K_s[p * 64 + ((blk ^ (p & 7)) << 3)] = cvt8(ka[u], kb[u]);
            }
        }
        // ---- write Vt (pair-packed b32), g(row)=(row+2*(row>>2))&7 ----
        // write guard p0 < KROWS: pad pairs [196,208) get explicit zeros
#pragma unroll
        for (int u = 0; u < 7; ++u) {
            int unit = t + 256 * u;
            int pp = unit >> 4, d4 = unit & 15;
            int p0 = pp * 2;
            if (p0 < KROWS) {
                int blk = p0 >> 3, sub = p0 & 7;
#pragma unroll
                for (int i = 0; i < 4; ++i) {
                    int row = d4 * 4 + i;
                    int g = (row + 2 * (row >> 2)) & 7;
                    *(unsigned*)&Vt_s[row * VST + (((blk ^ g) << 3) | sub)] = pkbf(va[u][i], vb[u][i]);
                }
            }
        }
        if (t < 224) bias_s[t] = (t < LP && mr != 0) ? 0.f : -1e30f;
        __syncthreads();  // B1: K + Vt + bias visible — last barrier of the frame

        // ---- QK^T: lane holds scores for q = w*16+lr, p = tl*16 + lg*4 + r ----
        f32x4 sc[13];
        __builtin_amdgcn_s_setprio(1);
#pragma unroll
        for (int tl = 0; tl < 13; ++tl) {
            int row = tl * 16 + lr;
            bf16x8 a0 = *(const bf16x8*)&K_s[row * 64 + ((lg ^ (lr & 7)) << 3)];
            bf16x8 a1 = *(const bf16x8*)&K_s[row * 64 + (((4 + lg) ^ (lr & 7)) << 3)];
            f32x4 z = {0.f, 0.f, 0.f, 0.f};
            z = __builtin_amdgcn_mfma_f32_16x16x32_bf16(a0, qb0, z, 0, 0, 0);
            sc[tl] = __builtin_amdgcn_mfma_f32_16x16x32_bf16(a1, qb1, z, 0, 0, 0);
        }
        __builtin_amdgcn_s_setprio(0);

        // ---- register softmax over 208 patches; P normalized in-register ----
        float mx = -FLT_MAX;
#pragma unroll
        for (int tl = 0; tl < 13; ++tl) {
            f32x4 bv = *(const f32x4*)&bias_s[tl * 16 + lg * 4];
#pragma unroll
            for (int r = 0; r < 4; ++r) {
                float sv = sc[tl][r] + bv[r];
                sc[tl][r] = sv;
                mx = fmaxf(mx, sv);
            }
        }
        mx = fmaxf(mx, __shfl_xor(mx, 16));
        mx = fmaxf(mx, __shfl_xor(mx, 32));
        float sum = 0.f;
#pragma unroll
        for (int tl = 0; tl < 13; ++tl) {
            float e0 = __expf(sc[tl][0] - mx);
            float e1 = __expf(sc[tl][1] - mx);
            float e2 = __expf(sc[tl][2] - mx);
            float e3 = __expf(sc[tl][3] - mx);
            sum += (e0 + e1) + (e2 + e3);
            sc[tl][0] = e0; sc[tl][1] = e1; sc[tl][2] = e2; sc[tl][3] = e3;
        }
        sum += __shfl_xor(sum, 16);
        sum += __shfl_xor(sum, 32);
        float inv = 1.0f / sum;
        unsigned pk[13][2];
#pragma unroll
        for (int tl = 0; tl < 13; ++tl) {
            pk[tl][0] = pkbf(sc[tl][0] * inv, sc[tl][1] * inv);
            pk[tl][1] = pkbf(sc[tl][2] * inv, sc[tl][3] * inv);
        }

        // ---- PV: A = pk fragments (16x16x16), C accumulator = mix ----
        __builtin_amdgcn_s_setprio(1);
#pragma unroll
        for (int dt = 0; dt < 4; ++dt) {
            int row = dt * 16 + lr;
            int g = (row + 2 * (row >> 2)) & 7;
            f32x4 acc = {mix[dt][0], mix[dt][1], mix[dt][2], mix[dt][3]};
#pragma unroll
            for (int kt = 0; kt < 13; ++kt) {
                int c0 = kt * 16 + lg * 4;
                s16x4 b = *(const s16x4*)&Vt_s[row * VST + ((((c0 >> 3) ^ g) << 3) | (c0 & 7))];
                s16x4 a = __builtin_bit_cast(s16x4, (u32x2){pk[kt][0], pk[kt][1]});
                acc = mfma16(a, b, acc);
            }
#pragma unroll
            for (int r = 0; r < 4; ++r) mix[dt][r] = acc[r];
        }
        __builtin_amdgcn_s_setprio(0);
    }

    // ---- accumulate into mix[n][q = w*16 + lg*4 + r][h*64 + dt*16 + lr] ----
#pragma unroll
    for (int dt = 0; dt < 4; ++dt)
#pragma unroll
        for (int r = 0; r < 4; ++r)
            atomicAdd(mix_g + ((size_t)n * QN + w * 16 + lg * 4 + r) * EE + h * DH + dt * 16 + lr,
                      mix[dt][r]);
}

// ---------------------------------------------------------------------------
extern "C" void kernel_launch(void* const* d_in, const int* in_sizes, int n_in,
                              void* d_out, int out_size, void* d_ws, size_t ws_size,
                              hipStream_t stream) {
    const float* q  = (const float*)d_in[0];
    const float* k  = (const float*)d_in[1];
    const float* v  = (const float*)d_in[2];
    const int*   m  = (const int*)d_in[3];
    const float* Wi = (const float*)d_in[4];
    const float* Wo = (const float*)d_in[5];

    float* out = (float*)d_out;
    float* qs  = out + (size_t)N_B * QN * EE;  // second output (qs_out), also attn input
    float* mix = (float*)d_ws;                 // 2048x768 fp32 scratch (atomic-accumulated)

    const int mix_n4 = (N_B * QN * EE) / 4;
    dim3 ggrid((N_B * QN) / 64, EE / 48);
    gemm_mfma<<<ggrid, 256, 0, stream>>>(q, Wi, qs);                                 // in-proj
    zero_f32<<<(mix_n4 + 255) / 256, 256, 0, stream>>>(mix, mix_n4);                 // zero mix
    attn_mfma<<<dim3(HN, FN / FPB, N_B), 256, 0, stream>>>(qs, k, v, m, mix);        // attention
    gemm_mfma<<<ggrid, 256, 0, stream>>>(mix, Wo, out);                              // out-proj
}